// Round 1
// baseline (708.150 us; speedup 1.0000x reference)
//
#include <hip/hip_runtime.h>

// XCA: cross-covariance attention, B=32 N=3136 D=384 H=8 C=48.
// Pipeline (all bf16 MFMA for matmul stages, fp32 accumulate):
//  1. convert x, qkv_w, proj_w fp32->bf16
//  2. QKV[b][e][n] = qkv_w(1152x384) . x_b^T          (gemm_bt, bf16 out, n-contig)
//  3. scales[b][e] = 1/max(||row||,eps) for e<768      (q and k rows)
//  4. S[bh][c][d]  = Q_bh(48x3136) . K_bh^T            (gemm_bt, K-dim = n)
//  5. attn = softmax(S * sq * sk * temp)
//  6. outT[b][n][e] = (attn . V)^T via MFMA (A=V^T staged transposed in LDS)
//  7. out = outT_b(3136x384) . proj_w^T + bias         (gemm_bt, fp32 out)

typedef __bf16 bf16x8 __attribute__((ext_vector_type(8)));
typedef float floatx4 __attribute__((ext_vector_type(4)));
typedef unsigned short u16;

#define B_ 32
#define N_ 3136
#define D_ 384
#define H_ 8
#define C_ 48
#define E3_ 1152

__device__ __forceinline__ u16 f2b(float f) {
  unsigned u = __builtin_bit_cast(unsigned, f);
  u += 0x7FFFu + ((u >> 16) & 1u);   // RNE
  return (u16)(u >> 16);
}
__device__ __forceinline__ float b2f(u16 s) {
  unsigned u = ((unsigned)s) << 16;
  return __builtin_bit_cast(float, u);
}

// ---------------- fp32 -> bf16 convert (vectorized, exact multiples of 4) ----
__global__ __launch_bounds__(256) void k_cvt(const float* __restrict__ in,
                                             u16* __restrict__ out, int n4) {
  int i = blockIdx.x * 256 + threadIdx.x;
  if (i < n4) {
    float4 v = ((const float4*)in)[i];
    ushort4 o;
    o.x = f2b(v.x); o.y = f2b(v.y); o.z = f2b(v.z); o.w = f2b(v.w);
    ((ushort4*)out)[i] = o;
  }
}

// ---------------- GEMM1: O[e][n] = sum_d W[e][d] X[n][d], bf16 out ----------
// grid: x = n-tiles(49), y = e-tiles(18), z = batch(32). 64x64 tile, 4 waves.
__global__ __launch_bounds__(256) void k_gemm_qkv(const u16* __restrict__ W,
                                                  const u16* __restrict__ X,
                                                  u16* __restrict__ O) {
  const int K = D_;
  int bz = blockIdx.z;
  int m0 = blockIdx.y * 64;
  int n0 = blockIdx.x * 64;
  const u16* Xb = X + (size_t)bz * N_ * D_;
  u16* Ob = O + (size_t)bz * E3_ * N_;

  __shared__ u16 As[64][32];
  __shared__ u16 Bs[64][32];

  int t = threadIdx.x;
  int row = t >> 2, chunk = (t & 3) * 8;
  int wid = t >> 6, lane = t & 63;
  int wm = (wid & 1) * 32, wn = (wid >> 1) * 32;
  int r = lane & 15, quad = lane >> 4, q8 = quad * 8;

  floatx4 acc[2][2] = {};
  for (int k0 = 0; k0 < K; k0 += 32) {
    int4 va = *(const int4*)(W + (size_t)(m0 + row) * K + k0 + chunk);
    int4 vb = *(const int4*)(Xb + (size_t)(n0 + row) * K + k0 + chunk);
    *(int4*)(&As[row][chunk]) = va;
    *(int4*)(&Bs[row][chunk]) = vb;
    __syncthreads();
    bf16x8 a0 = *(const bf16x8*)(&As[wm + r][q8]);
    bf16x8 a1 = *(const bf16x8*)(&As[wm + 16 + r][q8]);
    bf16x8 b0 = *(const bf16x8*)(&Bs[wn + r][q8]);
    bf16x8 b1 = *(const bf16x8*)(&Bs[wn + 16 + r][q8]);
    acc[0][0] = __builtin_amdgcn_mfma_f32_16x16x32_bf16(a0, b0, acc[0][0], 0, 0, 0);
    acc[0][1] = __builtin_amdgcn_mfma_f32_16x16x32_bf16(a0, b1, acc[0][1], 0, 0, 0);
    acc[1][0] = __builtin_amdgcn_mfma_f32_16x16x32_bf16(a1, b0, acc[1][0], 0, 0, 0);
    acc[1][1] = __builtin_amdgcn_mfma_f32_16x16x32_bf16(a1, b1, acc[1][1], 0, 0, 0);
    __syncthreads();
  }
  for (int mt = 0; mt < 2; mt++)
    for (int nt = 0; nt < 2; nt++)
      for (int j = 0; j < 4; j++) {
        int rr = m0 + wm + mt * 16 + quad * 4 + j;
        int cc = n0 + wn + nt * 16 + r;
        Ob[(size_t)rr * N_ + cc] = f2b(acc[mt][nt][j]);
      }
}

// ---------------- per-row L2 norm scales (q,k rows: e in [0,768)) -----------
__global__ __launch_bounds__(256) void k_norms(const u16* __restrict__ QKV,
                                               float* __restrict__ scales) {
  int rowid = blockIdx.x;          // 0 .. 32*768-1
  int b = rowid / 768, e = rowid % 768;
  const ushort4* p4 = (const ushort4*)(QKV + (size_t)b * E3_ * N_ + (size_t)e * N_);
  float ss = 0.f;
  for (int i = threadIdx.x; i < N_ / 4; i += 256) {
    ushort4 v = p4[i];
    float x0 = b2f(v.x), x1 = b2f(v.y), x2 = b2f(v.z), x3 = b2f(v.w);
    ss += x0 * x0 + x1 * x1 + x2 * x2 + x3 * x3;
  }
  for (int s = 32; s > 0; s >>= 1) ss += __shfl_down(ss, s);
  __shared__ float red[4];
  int wid = threadIdx.x >> 6, lane = threadIdx.x & 63;
  if (lane == 0) red[wid] = ss;
  __syncthreads();
  if (threadIdx.x == 0) {
    float tot = red[0] + red[1] + red[2] + red[3];
    scales[rowid] = 1.f / fmaxf(sqrtf(tot), 1e-12f);
  }
}

// ---------------- S[bh][c][d] = Q_bh . K_bh^T  (K-dim = n = 3136) -----------
// one block per (b,h); 64x64 tile covers the 48x48 output (zero-padded).
__global__ __launch_bounds__(256) void k_attn_s(const u16* __restrict__ QKV,
                                                float* __restrict__ S) {
  int bh = blockIdx.x, b = bh >> 3, h = bh & 7;
  const u16* Qb = QKV + (size_t)b * E3_ * N_ + (size_t)(h * C_) * N_;
  const u16* Kb = Qb + (size_t)D_ * N_;
  __shared__ u16 As[64][32];
  __shared__ u16 Bs[64][32];
  int t = threadIdx.x;
  int row = t >> 2, chunk = (t & 3) * 8;
  int wid = t >> 6, lane = t & 63;
  int wm = (wid & 1) * 32, wn = (wid >> 1) * 32;
  int r = lane & 15, quad = lane >> 4, q8 = quad * 8;
  floatx4 acc[2][2] = {};
  for (int k0 = 0; k0 < N_; k0 += 32) {
    int4 va = {0, 0, 0, 0}, vb = {0, 0, 0, 0};
    if (row < 48) {
      va = *(const int4*)(Qb + (size_t)row * N_ + k0 + chunk);
      vb = *(const int4*)(Kb + (size_t)row * N_ + k0 + chunk);
    }
    *(int4*)(&As[row][chunk]) = va;
    *(int4*)(&Bs[row][chunk]) = vb;
    __syncthreads();
    bf16x8 a0 = *(const bf16x8*)(&As[wm + r][q8]);
    bf16x8 a1 = *(const bf16x8*)(&As[wm + 16 + r][q8]);
    bf16x8 b0 = *(const bf16x8*)(&Bs[wn + r][q8]);
    bf16x8 b1 = *(const bf16x8*)(&Bs[wn + 16 + r][q8]);
    acc[0][0] = __builtin_amdgcn_mfma_f32_16x16x32_bf16(a0, b0, acc[0][0], 0, 0, 0);
    acc[0][1] = __builtin_amdgcn_mfma_f32_16x16x32_bf16(a0, b1, acc[0][1], 0, 0, 0);
    acc[1][0] = __builtin_amdgcn_mfma_f32_16x16x32_bf16(a1, b0, acc[1][0], 0, 0, 0);
    acc[1][1] = __builtin_amdgcn_mfma_f32_16x16x32_bf16(a1, b1, acc[1][1], 0, 0, 0);
    __syncthreads();
  }
  for (int mt = 0; mt < 2; mt++)
    for (int nt = 0; nt < 2; nt++)
      for (int j = 0; j < 4; j++) {
        int rr = wm + mt * 16 + quad * 4 + j;
        int cc = wn + nt * 16 + r;
        if (rr < 48 && cc < 48)
          S[(size_t)bh * 2304 + rr * 48 + cc] = acc[mt][nt][j];
      }
}

// ---------------- softmax over d with norm-scales + temperature -------------
__global__ __launch_bounds__(64) void k_softmax(const float* __restrict__ S,
                                                const float* __restrict__ scales,
                                                const float* __restrict__ temp,
                                                float* __restrict__ attn) {
  int bh = blockIdx.x, b = bh >> 3, h = bh & 7;
  int c = threadIdx.x;
  if (c >= 48) return;
  float sq = scales[b * 768 + h * 48 + c];
  float T = temp[h];
  const float* Srow = S + (size_t)bh * 2304 + c * 48;
  float v[48];
  float mx = -1e30f;
  for (int d = 0; d < 48; d++) {
    float sk = scales[b * 768 + 384 + h * 48 + d];
    float l = Srow[d] * sq * sk * T;
    v[d] = l;
    mx = fmaxf(mx, l);
  }
  float sum = 0.f;
  for (int d = 0; d < 48; d++) { v[d] = expf(v[d] - mx); sum += v[d]; }
  float inv = 1.f / sum;
  float* Arow = attn + (size_t)bh * 2304 + c * 48;
  for (int d = 0; d < 48; d++) Arow[d] = v[d] * inv;
}

// ---------------- outT[b][n][h*48+c] = sum_d attn[c][d] V[d][n] -------------
// grid: x = n-tiles(49), y = bh(256). MFMA: M=n(64), N=c(48), K=d(48 pad 64).
__global__ __launch_bounds__(256) void k_attn_v(const u16* __restrict__ QKV,
                                                const float* __restrict__ attn,
                                                u16* __restrict__ outT) {
  int bh = blockIdx.y, b = bh >> 3, h = bh & 7;
  int n0 = blockIdx.x * 64;
  const u16* V = QKV + (size_t)b * E3_ * N_ + (size_t)(2 * D_ + h * C_) * N_;
  __shared__ u16 Vt[64][64];   // [n_local][d], zero-padded d 48..63
  __shared__ u16 Aw[48][64];   // attn [c][d] bf16, zero-padded d 48..63
  int t = threadIdx.x;
  // zero-fill both LDS tiles
  for (int i = t; i < 64 * 64 * 2 / 16; i += 256) ((int4*)Vt)[i] = int4{0, 0, 0, 0};
  for (int i = t; i < 48 * 64 * 2 / 16; i += 256) ((int4*)Aw)[i] = int4{0, 0, 0, 0};
  __syncthreads();
  // stage V transposed: 48 d-rows x 16 ushort4 chunks
  for (int idx = t; idx < 768; idx += 256) {
    int d = idx >> 4, c4 = (idx & 15) * 4;
    ushort4 v = *(const ushort4*)(V + (size_t)d * N_ + n0 + c4);
    Vt[c4 + 0][d] = v.x; Vt[c4 + 1][d] = v.y;
    Vt[c4 + 2][d] = v.z; Vt[c4 + 3][d] = v.w;
  }
  // stage attn fp32 -> bf16
  for (int i = t; i < 2304; i += 256) {
    int c = i / 48, d = i - c * 48;
    Aw[c][d] = f2b(attn[(size_t)bh * 2304 + i]);
  }
  __syncthreads();
  int wid = t >> 6, lane = t & 63;
  int r = lane & 15, quad = lane >> 4, q8 = quad * 8;
  floatx4 acc[3] = {};
  for (int ks = 0; ks < 2; ks++) {
    bf16x8 a = *(const bf16x8*)(&Vt[wid * 16 + r][ks * 32 + q8]);
    for (int nt = 0; nt < 3; nt++) {
      bf16x8 bb = *(const bf16x8*)(&Aw[nt * 16 + r][ks * 32 + q8]);
      acc[nt] = __builtin_amdgcn_mfma_f32_16x16x32_bf16(a, bb, acc[nt], 0, 0, 0);
    }
  }
  u16* Ob = outT + (size_t)b * N_ * D_;
  for (int nt = 0; nt < 3; nt++)
    for (int j = 0; j < 4; j++) {
      int n = n0 + wid * 16 + quad * 4 + j;
      int e = h * C_ + nt * 16 + r;
      Ob[(size_t)n * D_ + e] = f2b(acc[nt][j]);
    }
}

// ---------------- proj: Y[n][f] = sum_e outT[n][e] P[f][e] + bias[f] --------
// grid: x = f-tiles(6), y = token-tiles(49), z = batch(32)
__global__ __launch_bounds__(256) void k_gemm_proj(const u16* __restrict__ OT,
                                                   const u16* __restrict__ P,
                                                   const float* __restrict__ bias,
                                                   float* __restrict__ Y) {
  const int K = D_;
  int bz = blockIdx.z;
  int m0 = blockIdx.y * 64;
  int n0 = blockIdx.x * 64;
  const u16* Ab = OT + (size_t)bz * N_ * D_;
  float* Yb = Y + (size_t)bz * N_ * D_;
  __shared__ u16 As[64][32];
  __shared__ u16 Bs[64][32];
  int t = threadIdx.x;
  int row = t >> 2, chunk = (t & 3) * 8;
  int wid = t >> 6, lane = t & 63;
  int wm = (wid & 1) * 32, wn = (wid >> 1) * 32;
  int r = lane & 15, quad = lane >> 4, q8 = quad * 8;
  floatx4 acc[2][2] = {};
  for (int k0 = 0; k0 < K; k0 += 32) {
    int4 va = *(const int4*)(Ab + (size_t)(m0 + row) * K + k0 + chunk);
    int4 vb = *(const int4*)(P + (size_t)(n0 + row) * K + k0 + chunk);
    *(int4*)(&As[row][chunk]) = va;
    *(int4*)(&Bs[row][chunk]) = vb;
    __syncthreads();
    bf16x8 a0 = *(const bf16x8*)(&As[wm + r][q8]);
    bf16x8 a1 = *(const bf16x8*)(&As[wm + 16 + r][q8]);
    bf16x8 b0 = *(const bf16x8*)(&Bs[wn + r][q8]);
    bf16x8 b1 = *(const bf16x8*)(&Bs[wn + 16 + r][q8]);
    acc[0][0] = __builtin_amdgcn_mfma_f32_16x16x32_bf16(a0, b0, acc[0][0], 0, 0, 0);
    acc[0][1] = __builtin_amdgcn_mfma_f32_16x16x32_bf16(a0, b1, acc[0][1], 0, 0, 0);
    acc[1][0] = __builtin_amdgcn_mfma_f32_16x16x32_bf16(a1, b0, acc[1][0], 0, 0, 0);
    acc[1][1] = __builtin_amdgcn_mfma_f32_16x16x32_bf16(a1, b1, acc[1][1], 0, 0, 0);
    __syncthreads();
  }
  for (int mt = 0; mt < 2; mt++)
    for (int nt = 0; nt < 2; nt++)
      for (int j = 0; j < 4; j++) {
        int rr = m0 + wm + mt * 16 + quad * 4 + j;
        int cc = n0 + wn + nt * 16 + r;
        Yb[(size_t)rr * D_ + cc] = acc[mt][nt][j] + bias[cc];
      }
}

extern "C" void kernel_launch(void* const* d_in, const int* in_sizes, int n_in,
                              void* d_out, int out_size, void* d_ws, size_t ws_size,
                              hipStream_t stream) {
  const float* x      = (const float*)d_in[0];   // 32*3136*384
  const float* qkv_w  = (const float*)d_in[1];   // 1152*384
  const float* temp   = (const float*)d_in[2];   // 8
  const float* proj_w = (const float*)d_in[3];   // 384*384
  const float* proj_b = (const float*)d_in[4];   // 384
  float* out = (float*)d_out;

  // workspace layout (bytes), total ~314.3 MB
  char* ws = (char*)d_ws;
  u16*   qkv    = (u16*)(ws);                    // 231,211,008
  u16*   xbf    = (u16*)(ws + 231211008);        //  77,070,336 (aliased by outT)
  u16*   wbf    = (u16*)(ws + 308281344);        //     884,736
  u16*   pwbf   = (u16*)(ws + 309166080);        //     294,912
  float* scales = (float*)(ws + 309460992);      //      98,304
  float* S      = (float*)(ws + 309559296);      //   2,359,296
  float* attn   = (float*)(ws + 311918592);      //   2,359,296
  u16*   outT   = xbf;  // x_bf16 dead after gemm_qkv; reuse for outT

  k_cvt<<<38535168 / 4 / 256, 256, 0, stream>>>(x, xbf, 38535168 / 4);
  k_cvt<<<442368 / 4 / 256, 256, 0, stream>>>(qkv_w, wbf, 442368 / 4);
  k_cvt<<<147456 / 4 / 256, 256, 0, stream>>>(proj_w, pwbf, 147456 / 4);

  k_gemm_qkv<<<dim3(49, 18, 32), 256, 0, stream>>>(wbf, xbf, qkv);
  k_norms<<<32 * 768, 256, 0, stream>>>(qkv, scales);
  k_attn_s<<<256, 256, 0, stream>>>(qkv, S);
  k_softmax<<<256, 64, 0, stream>>>(S, scales, temp, attn);
  k_attn_v<<<dim3(49, 256), 256, 0, stream>>>(qkv, attn, outT);
  k_gemm_proj<<<dim3(6, 49, 32), 256, 0, stream>>>(outT, pwbf, proj_b, out);
}

// Round 2
// 583.426 us; speedup vs baseline: 1.2138x; 1.2138x over previous
//
#include <hip/hip_runtime.h>

// XCA: cross-covariance attention, B=32 N=3136 D=384 H=8 C=48.
// Round 2: m97-style GEMMs (128x128 tile, global_load_lds w16), QKV stored as
// [e][g] with g=b*N+n (one flat 1152x100352x384 GEMM), split-K attn_s with
// fused L2-norm sumsq, proj as one flat 100352x384x384 GEMM.

typedef __bf16 bf16x8 __attribute__((ext_vector_type(8)));
typedef float floatx4 __attribute__((ext_vector_type(4)));
typedef unsigned short u16;

#define B_ 32
#define N_ 3136
#define D_ 384
#define H_ 8
#define C_ 48
#define E3_ 1152
#define BN_ 100352   // B_*N_

__device__ __forceinline__ u16 f2b(float f) {
  unsigned u = __builtin_bit_cast(unsigned, f);
  u += 0x7FFFu + ((u >> 16) & 1u);   // RNE
  return (u16)(u >> 16);
}
__device__ __forceinline__ float b2f(u16 s) {
  unsigned u = ((unsigned)s) << 16;
  return __builtin_bit_cast(float, u);
}
__device__ __forceinline__ void gload16(const u16* g, u16* l) {
  __builtin_amdgcn_global_load_lds(
      (const __attribute__((address_space(1))) void*)g,
      (__attribute__((address_space(3))) void*)l, 16, 0, 0);
}

// ---------------- fp32 -> bf16 convert ----------------
__global__ __launch_bounds__(256) void k_cvt(const float* __restrict__ in,
                                             u16* __restrict__ out, int n4) {
  int i = blockIdx.x * 256 + threadIdx.x;
  if (i < n4) {
    float4 v = ((const float4*)in)[i];
    ushort4 o;
    o.x = f2b(v.x); o.y = f2b(v.y); o.z = f2b(v.z); o.w = f2b(v.w);
    ((ushort4*)out)[i] = o;
  }
}

// ---------------- GEMM1: O[e][g] = sum_d W[e][d] X[g][d], bf16 out ----------
// m97 structure: 128x128 tile, BK=32, global_load_lds w16, 4 waves, 4x4 accs.
// grid: x = e-tiles(9)  [small dim fastest -> X tile L2-reused], y = g-tiles(784)
__global__ __launch_bounds__(256) void k_gemm_qkv(const u16* __restrict__ W,
                                                  const u16* __restrict__ X,
                                                  u16* __restrict__ O) {
  const int K = D_;
  int m0 = blockIdx.x * 128;   // e
  int n0 = blockIdx.y * 128;   // g
  __shared__ u16 As[128][32];
  __shared__ u16 Bs[128][32];
  int t = threadIdx.x, wid = t >> 6, lane = t & 63;
  int srow = wid * 32 + (lane >> 2);      // staging row (call 0); call 1 = +16
  int scol = (lane & 3) * 8;
  int wm = (wid & 1) * 64, wn = (wid >> 1) * 64;
  int r = lane & 15, quad = lane >> 4, q8 = quad * 8;

  const u16* gA = W + (size_t)(m0 + srow) * K + scol;
  const u16* gB = X + (size_t)(n0 + srow) * K + scol;
  u16* lA0 = &As[wid * 32][0];
  u16* lA1 = &As[wid * 32 + 16][0];
  u16* lB0 = &Bs[wid * 32][0];
  u16* lB1 = &Bs[wid * 32 + 16][0];

  floatx4 acc[4][4] = {};
  for (int k0 = 0; k0 < K; k0 += 32) {
    gload16(gA + k0, lA0);
    gload16(gA + k0 + 16 * K, lA1);
    gload16(gB + k0, lB0);
    gload16(gB + k0 + 16 * K, lB1);
    __syncthreads();
    bf16x8 af[4], bf[4];
    for (int i = 0; i < 4; i++) af[i] = *(const bf16x8*)(&As[wm + i * 16 + r][q8]);
    for (int j = 0; j < 4; j++) bf[j] = *(const bf16x8*)(&Bs[wn + j * 16 + r][q8]);
    for (int i = 0; i < 4; i++)
      for (int j = 0; j < 4; j++)
        acc[i][j] = __builtin_amdgcn_mfma_f32_16x16x32_bf16(af[i], bf[j], acc[i][j], 0, 0, 0);
    __syncthreads();
  }
  for (int i = 0; i < 4; i++)
    for (int j = 0; j < 4; j++)
      for (int v = 0; v < 4; v++) {
        int rr = m0 + wm + i * 16 + quad * 4 + v;
        int cc = n0 + wn + j * 16 + r;
        O[(size_t)rr * BN_ + cc] = f2b(acc[i][j][v]);
      }
}

// ---------------- attn_s: split-K, fused sumsq ------------------------------
// S[bh][c][d] += Q_bh[c][ns..ns+448) . K_bh[d][..]^T ; ssq_{q,k} += row sumsq
// grid: x = bh(256), y = split(7). 64x64 padded tile, 4 waves.
__global__ __launch_bounds__(256) void k_attn_s(const u16* __restrict__ QKV,
                                                float* __restrict__ S,
                                                float* __restrict__ ssq) {
  int bh = blockIdx.x, b = bh >> 3, h = bh & 7;
  int ns = blockIdx.y * 448;
  const u16* Qb = QKV + (size_t)(h * C_) * BN_ + b * N_ + ns;
  const u16* Kb = QKV + (size_t)(D_ + h * C_) * BN_ + b * N_ + ns;
  __shared__ u16 As[64][32];
  __shared__ u16 Bs[64][32];
  int t = threadIdx.x;
  int row = t >> 2, chunk = (t & 3) * 8;
  int wid = t >> 6, lane = t & 63;
  int wm = (wid & 1) * 32, wn = (wid >> 1) * 32;
  int r = lane & 15, quad = lane >> 4, q8 = quad * 8;
  float sq_acc = 0.f, sk_acc = 0.f;
  floatx4 acc[2][2] = {};
  for (int k0 = 0; k0 < 448; k0 += 32) {
    int4 va = {0, 0, 0, 0}, vb = {0, 0, 0, 0};
    if (row < 48) {
      va = *(const int4*)(Qb + (size_t)row * BN_ + k0 + chunk);
      vb = *(const int4*)(Kb + (size_t)row * BN_ + k0 + chunk);
    }
    *(int4*)(&As[row][chunk]) = va;
    *(int4*)(&Bs[row][chunk]) = vb;
    const u16* pa = (const u16*)&va;
    const u16* pb = (const u16*)&vb;
    for (int i = 0; i < 8; i++) {
      float fa = b2f(pa[i]), fb = b2f(pb[i]);
      sq_acc += fa * fa; sk_acc += fb * fb;
    }
    __syncthreads();
    bf16x8 a0 = *(const bf16x8*)(&As[wm + r][q8]);
    bf16x8 a1 = *(const bf16x8*)(&As[wm + 16 + r][q8]);
    bf16x8 b0 = *(const bf16x8*)(&Bs[wn + r][q8]);
    bf16x8 b1 = *(const bf16x8*)(&Bs[wn + 16 + r][q8]);
    acc[0][0] = __builtin_amdgcn_mfma_f32_16x16x32_bf16(a0, b0, acc[0][0], 0, 0, 0);
    acc[0][1] = __builtin_amdgcn_mfma_f32_16x16x32_bf16(a0, b1, acc[0][1], 0, 0, 0);
    acc[1][0] = __builtin_amdgcn_mfma_f32_16x16x32_bf16(a1, b0, acc[1][0], 0, 0, 0);
    acc[1][1] = __builtin_amdgcn_mfma_f32_16x16x32_bf16(a1, b1, acc[1][1], 0, 0, 0);
    __syncthreads();
  }
  // sumsq: 4 threads per row -> lanes (t&~3)..+3 within a wave
  sq_acc += __shfl_xor(sq_acc, 1); sq_acc += __shfl_xor(sq_acc, 2);
  sk_acc += __shfl_xor(sk_acc, 1); sk_acc += __shfl_xor(sk_acc, 2);
  if ((t & 3) == 0 && row < 48) {
    atomicAdd(&ssq[bh * 48 + row], sq_acc);
    atomicAdd(&ssq[12288 + bh * 48 + row], sk_acc);
  }
  for (int mt = 0; mt < 2; mt++)
    for (int nt = 0; nt < 2; nt++)
      for (int v = 0; v < 4; v++) {
        int rr = wm + mt * 16 + quad * 4 + v;
        int cc = wn + nt * 16 + r;
        if (rr < 48 && cc < 48)
          atomicAdd(&S[(size_t)bh * 2304 + rr * 48 + cc], acc[mt][nt][v]);
      }
}

// ---------------- softmax over d with norm-scales + temperature -------------
__global__ __launch_bounds__(64) void k_softmax(const float* __restrict__ S,
                                                const float* __restrict__ ssq,
                                                const float* __restrict__ temp,
                                                float* __restrict__ attn) {
  int bh = blockIdx.x, h = bh & 7;
  int c = threadIdx.x;
  if (c >= 48) return;
  float sq = 1.f / fmaxf(sqrtf(ssq[bh * 48 + c]), 1e-12f);
  float T = temp[h];
  const float* Srow = S + (size_t)bh * 2304 + c * 48;
  float v[48];
  float mx = -1e30f;
  for (int d = 0; d < 48; d++) {
    float sk = 1.f / fmaxf(sqrtf(ssq[12288 + bh * 48 + d]), 1e-12f);
    float l = Srow[d] * sq * sk * T;
    v[d] = l;
    mx = fmaxf(mx, l);
  }
  float sum = 0.f;
  for (int d = 0; d < 48; d++) { v[d] = expf(v[d] - mx); sum += v[d]; }
  float inv = 1.f / sum;
  float* Arow = attn + (size_t)bh * 2304 + c * 48;
  for (int d = 0; d < 48; d++) Arow[d] = v[d] * inv;
}

// ---------------- outT[g][h*48+c] = sum_d attn[c][d] V[d][n] ---------------
// grid: x = n-tiles(49), y = bh(256). MFMA: M=n(64), N=c(48), K=d(48 pad 64).
__global__ __launch_bounds__(256) void k_attn_v(const u16* __restrict__ QKV,
                                                const float* __restrict__ attn,
                                                u16* __restrict__ outT) {
  int bh = blockIdx.y, b = bh >> 3, h = bh & 7;
  int n0 = blockIdx.x * 64;
  const u16* V = QKV + (size_t)(2 * D_ + h * C_) * BN_ + b * N_;
  __shared__ u16 Vt[64][64];   // [n_local][d], zero-padded d 48..63
  __shared__ u16 Aw[48][64];   // attn [c][d] bf16, zero-padded d 48..63
  int t = threadIdx.x;
  for (int i = t; i < 64 * 64 * 2 / 16; i += 256) ((int4*)Vt)[i] = int4{0, 0, 0, 0};
  for (int i = t; i < 48 * 64 * 2 / 16; i += 256) ((int4*)Aw)[i] = int4{0, 0, 0, 0};
  __syncthreads();
  for (int idx = t; idx < 768; idx += 256) {
    int d = idx >> 4, c4 = (idx & 15) * 4;
    ushort4 v = *(const ushort4*)(V + (size_t)d * BN_ + n0 + c4);
    Vt[c4 + 0][d] = v.x; Vt[c4 + 1][d] = v.y;
    Vt[c4 + 2][d] = v.z; Vt[c4 + 3][d] = v.w;
  }
  for (int i = t; i < 2304; i += 256) {
    int c = i / 48, d = i - c * 48;
    Aw[c][d] = f2b(attn[(size_t)bh * 2304 + i]);
  }
  __syncthreads();
  int wid = t >> 6, lane = t & 63;
  int r = lane & 15, quad = lane >> 4, q8 = quad * 8;
  floatx4 acc[3] = {};
  for (int ks = 0; ks < 2; ks++) {
    bf16x8 a = *(const bf16x8*)(&Vt[wid * 16 + r][ks * 32 + q8]);
    for (int nt = 0; nt < 3; nt++) {
      bf16x8 bb = *(const bf16x8*)(&Aw[nt * 16 + r][ks * 32 + q8]);
      acc[nt] = __builtin_amdgcn_mfma_f32_16x16x32_bf16(a, bb, acc[nt], 0, 0, 0);
    }
  }
  u16* Ob = outT + (size_t)(b * N_) * D_;
  for (int nt = 0; nt < 3; nt++)
    for (int j = 0; j < 4; j++) {
      int n = n0 + wid * 16 + quad * 4 + j;
      int e = h * C_ + nt * 16 + r;
      Ob[(size_t)n * D_ + e] = f2b(acc[nt][j]);
    }
}

// ---------------- proj: Y[g][f] = sum_e OT[g][e] P[f][e] + bias[f] ---------
// m97 structure. grid: x = f-tiles(3) [small fastest], y = g-tiles(784)
__global__ __launch_bounds__(256) void k_gemm_proj(const u16* __restrict__ OT,
                                                   const u16* __restrict__ P,
                                                   const float* __restrict__ bias,
                                                   float* __restrict__ Y) {
  const int K = D_;
  int n0 = blockIdx.x * 128;   // f
  int m0 = blockIdx.y * 128;   // g
  __shared__ u16 As[128][32];
  __shared__ u16 Bs[128][32];
  int t = threadIdx.x, wid = t >> 6, lane = t & 63;
  int srow = wid * 32 + (lane >> 2);
  int scol = (lane & 3) * 8;
  int wm = (wid & 1) * 64, wn = (wid >> 1) * 64;
  int r = lane & 15, quad = lane >> 4, q8 = quad * 8;

  const u16* gA = OT + (size_t)(m0 + srow) * K + scol;
  const u16* gB = P + (size_t)(n0 + srow) * K + scol;
  u16* lA0 = &As[wid * 32][0];
  u16* lA1 = &As[wid * 32 + 16][0];
  u16* lB0 = &Bs[wid * 32][0];
  u16* lB1 = &Bs[wid * 32 + 16][0];

  floatx4 acc[4][4] = {};
  for (int k0 = 0; k0 < K; k0 += 32) {
    gload16(gA + k0, lA0);
    gload16(gA + k0 + 16 * K, lA1);
    gload16(gB + k0, lB0);
    gload16(gB + k0 + 16 * K, lB1);
    __syncthreads();
    bf16x8 af[4], bf[4];
    for (int i = 0; i < 4; i++) af[i] = *(const bf16x8*)(&As[wm + i * 16 + r][q8]);
    for (int j = 0; j < 4; j++) bf[j] = *(const bf16x8*)(&Bs[wn + j * 16 + r][q8]);
    for (int i = 0; i < 4; i++)
      for (int j = 0; j < 4; j++)
        acc[i][j] = __builtin_amdgcn_mfma_f32_16x16x32_bf16(af[i], bf[j], acc[i][j], 0, 0, 0);
    __syncthreads();
  }
  for (int i = 0; i < 4; i++)
    for (int j = 0; j < 4; j++) {
      int cc = n0 + wn + j * 16 + r;
      float bv = bias[cc];
      for (int v = 0; v < 4; v++) {
        int rr = m0 + wm + i * 16 + quad * 4 + v;
        Y[(size_t)rr * D_ + cc] = acc[i][j][v] + bv;
      }
    }
}

extern "C" void kernel_launch(void* const* d_in, const int* in_sizes, int n_in,
                              void* d_out, int out_size, void* d_ws, size_t ws_size,
                              hipStream_t stream) {
  const float* x      = (const float*)d_in[0];   // 32*3136*384
  const float* qkv_w  = (const float*)d_in[1];   // 1152*384
  const float* temp   = (const float*)d_in[2];   // 8
  const float* proj_w = (const float*)d_in[3];   // 384*384
  const float* proj_b = (const float*)d_in[4];   // 384
  float* out = (float*)d_out;

  // workspace layout (bytes)
  char* ws = (char*)d_ws;
  u16*   qkv    = (u16*)(ws);                    // 231,211,008  [e][g] bf16
  u16*   xbf    = (u16*)(ws + 231211008);        //  77,070,336  (aliased by outT)
  u16*   wbf    = (u16*)(ws + 308281344);        //     884,736
  u16*   pwbf   = (u16*)(ws + 309166080);        //     294,912
  float* S      = (float*)(ws + 309460992);      //   2,359,296  [bh][48][48]
  float* ssq    = (float*)(ws + 311820288);      //      98,304  [2][256][48]
  float* attn   = (float*)(ws + 311918592);      //   2,359,296
  u16*   outT   = xbf;  // x_bf16 dead after gemm_qkv; reuse for outT [g][e]

  hipMemsetAsync(S, 0, 2359296 + 98304, stream);  // zero S + ssq (adjacent)

  k_cvt<<<38535168 / 4 / 256, 256, 0, stream>>>(x, xbf, 38535168 / 4);
  k_cvt<<<442368 / 4 / 256, 256, 0, stream>>>(qkv_w, wbf, 442368 / 4);
  k_cvt<<<147456 / 4 / 256, 256, 0, stream>>>(proj_w, pwbf, 147456 / 4);

  k_gemm_qkv<<<dim3(9, 784), 256, 0, stream>>>(wbf, xbf, qkv);
  k_attn_s<<<dim3(256, 7), 256, 0, stream>>>(qkv, S, ssq);
  k_softmax<<<256, 64, 0, stream>>>(S, ssq, temp, attn);
  k_attn_v<<<dim3(49, 256), 256, 0, stream>>>(qkv, attn, outT);
  k_gemm_proj<<<dim3(3, 784), 256, 0, stream>>>(outT, pwbf, proj_b, out);
}